// Round 1
// baseline (329.841 us; speedup 1.0000x reference)
//
#include <hip/hip_runtime.h>
#include <stdint.h>

// Problem constants
#define M_BATCH 32768
#define N_OUT   1024
#define K_IN    1024

// GEMM tile
#define BM 128
#define BN 128
#define BK 64

typedef __attribute__((ext_vector_type(8))) short  short8;
typedef __attribute__((ext_vector_type(4))) float  f32x4;

__device__ __forceinline__ unsigned short f2bf(float f) {
    __bf16 h = (__bf16)f;                       // fptrunc; gfx950 lowers to v_cvt_pk_bf16_f32
    return __builtin_bit_cast(unsigned short, h);
}

// ---------------------------------------------------------------------------
// Kernel 1: materialize W (bf16 bits) from eigens.
// W[y*8+j][xb*8+c] = eigens[y][xb][(j-c)&7]
// One thread per (y, xb) cell -> writes an 8x8 block, all-static register
// indexing (rule #20: no runtime-indexed local arrays).
// ---------------------------------------------------------------------------
__global__ __launch_bounds__(256) void build_w(const float* __restrict__ eig,
                                               unsigned short* __restrict__ W) {
    int tid = blockIdx.x * 256 + threadIdx.x;   // 0..16383
    int y  = tid >> 7;
    int xb = tid & 127;
    const float* e = eig + (size_t)((y << 7) + xb) * 8;
    f32x4 e0 = *reinterpret_cast<const f32x4*>(e);
    f32x4 e1 = *reinterpret_cast<const f32x4*>(e + 4);
    float ev[8] = {e0[0], e0[1], e0[2], e0[3], e1[0], e1[1], e1[2], e1[3]};
#pragma unroll
    for (int j = 0; j < 8; ++j) {
        alignas(16) unsigned short wv[8];
#pragma unroll
        for (int c = 0; c < 8; ++c) wv[c] = f2bf(ev[(j - c) & 7]);
        *reinterpret_cast<uint4*>(W + (size_t)(y * 8 + j) * K_IN + xb * 8) =
            *reinterpret_cast<const uint4*>(wv);
    }
}

// ---------------------------------------------------------------------------
// Kernel 2: C[M,N] = A[M,K](f32, cvt->bf16) * W[N,K]^T (bf16), fp32 out.
// 128x128 tile, BK=64, 4 waves (2x2 of 64x64), mfma_f32_16x16x32_bf16,
// XOR-swizzled LDS (slot ^= row&7 on 16B units -> conflict-free ds_read_b128),
// XCD-aware bijective block swizzle (nwg=2048, %8==0).
// ---------------------------------------------------------------------------
__global__ __launch_bounds__(256) void gemm_bt(const float* __restrict__ A,
                                               const unsigned short* __restrict__ W,
                                               float* __restrict__ C) {
    __shared__ unsigned short Alds[BM * BK];    // 16 KiB
    __shared__ unsigned short Blds[BN * BK];    // 16 KiB

    // XCD swizzle: each XCD gets a contiguous M-chunk; all 8 N-blocks of an
    // M-row land on the same XCD -> A panel stays in that XCD's L2.
    const int bid  = blockIdx.x;                 // 0..2047
    const int swz  = (bid & 7) * 256 + (bid >> 3);
    const int nblk = swz & 7;                    // 0..7
    const int mblk = swz >> 3;                   // 0..255
    const int brow = mblk * BM;
    const int bcol = nblk * BN;

    const int tid  = threadIdx.x;
    const int lane = tid & 63;
    const int wv   = tid >> 6;                   // wave 0..3
    const int wm   = wv >> 1;                    // 0..1
    const int wn   = wv & 1;                     // 0..1

    f32x4 acc[4][4];
    const f32x4 zero = {0.f, 0.f, 0.f, 0.f};
#pragma unroll
    for (int i = 0; i < 4; ++i)
#pragma unroll
        for (int j = 0; j < 4; ++j) acc[i][j] = zero;

    // Staging map: 16B unit u = it*256 + tid; row = u>>3 (=it*32 + tid>>3),
    // slot = u&7 (= tid&7). Swizzled source chunk k8 = slot ^ (row&7)
    // (row&7 constant across it since stride 32). LDS dest stays linear-ish
    // (row,slot); the SOURCE k-chunk is permuted => write==read swizzle.
    const int srow  = tid >> 3;                  // 0..31
    const int sslot = tid & 7;
    const int sk8   = sslot ^ (srow & 7);
    const float*          Abase = A + (size_t)(brow + srow) * K_IN + sk8 * 8;
    const unsigned short* Wbase = W + (size_t)(bcol + srow) * K_IN + sk8 * 8;
    unsigned short* AldsW = Alds + srow * BK + sslot * 8;
    unsigned short* BldsW = Blds + srow * BK + sslot * 8;

    for (int kt = 0; kt < K_IN; kt += BK) {
        __syncthreads();                         // previous tile fully consumed
        // ---- stage A (f32 -> bf16 in regs -> LDS) : 4 units/thread
#pragma unroll
        for (int it = 0; it < 4; ++it) {
            const float* src = Abase + (size_t)it * 32 * K_IN + kt;
            f32x4 v0 = *reinterpret_cast<const f32x4*>(src);
            f32x4 v1 = *reinterpret_cast<const f32x4*>(src + 4);
            short8 b;
#pragma unroll
            for (int i = 0; i < 4; ++i) b[i]     = (short)f2bf(v0[i]);
#pragma unroll
            for (int i = 0; i < 4; ++i) b[i + 4] = (short)f2bf(v1[i]);
            *reinterpret_cast<short8*>(AldsW + it * 32 * BK) = b;
        }
        // ---- stage B (bf16 16B copies) : 4 units/thread
#pragma unroll
        for (int it = 0; it < 4; ++it) {
            const unsigned short* src = Wbase + (size_t)it * 32 * K_IN + kt;
            short8 b = *reinterpret_cast<const short8*>(src);
            *reinterpret_cast<short8*>(BldsW + it * 32 * BK) = b;
        }
        __syncthreads();                         // tile visible
        // ---- compute: 2 k-substeps x (8 ds_read_b128 + 16 MFMA)
#pragma unroll
        for (int ks = 0; ks < 2; ++ks) {
            short8 af[4], bfr[4];
            const int cb = ks * 4 + (lane >> 4); // 16B k-chunk index 0..7
#pragma unroll
            for (int mt = 0; mt < 4; ++mt) {
                int row  = wm * 64 + mt * 16 + (lane & 15);
                int slot = cb ^ (row & 7);
                af[mt] = *reinterpret_cast<const short8*>(Alds + row * BK + slot * 8);
            }
#pragma unroll
            for (int nt = 0; nt < 4; ++nt) {
                int row  = wn * 64 + nt * 16 + (lane & 15);
                int slot = cb ^ (row & 7);
                bfr[nt] = *reinterpret_cast<const short8*>(Blds + row * BK + slot * 8);
            }
#pragma unroll
            for (int mt = 0; mt < 4; ++mt)
#pragma unroll
                for (int nt = 0; nt < 4; ++nt)
                    acc[mt][nt] = __builtin_amdgcn_mfma_f32_16x16x32_bf16(
                        af[mt], bfr[nt], acc[mt][nt], 0, 0, 0);
        }
    }

    // ---- epilogue: C/D layout col = lane&15, row = (lane>>4)*4 + reg
#pragma unroll
    for (int mt = 0; mt < 4; ++mt) {
#pragma unroll
        for (int nt = 0; nt < 4; ++nt) {
            int col = bcol + wn * 64 + nt * 16 + (lane & 15);
#pragma unroll
            for (int r = 0; r < 4; ++r) {
                int row = brow + wm * 64 + mt * 16 + (lane >> 4) * 4 + r;
                C[(size_t)row * N_OUT + col] = acc[mt][nt][r];
            }
        }
    }
}

extern "C" void kernel_launch(void* const* d_in, const int* in_sizes, int n_in,
                              void* d_out, int out_size, void* d_ws, size_t ws_size,
                              hipStream_t stream) {
    const float* x   = (const float*)d_in[0];    // [32768,1024] f32
    const float* eig = (const float*)d_in[1];    // [128,128,8]  f32
    float* out = (float*)d_out;                  // [32768,1024] f32
    unsigned short* W = (unsigned short*)d_ws;   // 1024*1024 bf16 = 2 MiB scratch
    if (ws_size < (size_t)N_OUT * K_IN * sizeof(unsigned short)) return;

    hipLaunchKernelGGL(build_w, dim3((16384 + 255) / 256), dim3(256), 0, stream,
                       eig, W);
    hipLaunchKernelGGL(gemm_bt, dim3((M_BATCH / BM) * (N_OUT / BN)), dim3(256),
                       0, stream, x, W, out);
}

// Round 2
// 298.216 us; speedup vs baseline: 1.1060x; 1.1060x over previous
//
#include <hip/hip_runtime.h>
#include <stdint.h>

// Problem constants
#define M_BATCH 32768
#define N_OUT   1024
#define K_IN    1024

// GEMM tile
#define BM 128
#define BN 128
#define BK 64

typedef __attribute__((ext_vector_type(8))) short  short8;
typedef __attribute__((ext_vector_type(4))) float  f32x4;

__device__ __forceinline__ unsigned short f2bf(float f) {
    __bf16 h = (__bf16)f;
    return __builtin_bit_cast(unsigned short, h);
}

typedef const __attribute__((address_space(1))) unsigned int* gas_ptr;
typedef __attribute__((address_space(3))) unsigned int*       las_ptr;

__device__ __forceinline__ void gload_lds16(const void* g, void* l) {
    // async global->LDS, 16B/lane; LDS dest = wave-uniform base + lane*16
    __builtin_amdgcn_global_load_lds((gas_ptr)g, (las_ptr)l, 16, 0, 0);
}

// ---------------------------------------------------------------------------
// Kernel 0: x (f32) -> bf16, grid-stride, 8 elems/thread/iter.
// ---------------------------------------------------------------------------
__global__ __launch_bounds__(256) void cvt_x(const float* __restrict__ x,
                                             unsigned short* __restrict__ xb) {
    const size_t total8 = (size_t)M_BATCH * K_IN / 8;
    const size_t stride = (size_t)gridDim.x * 256;
    for (size_t i = (size_t)blockIdx.x * 256 + threadIdx.x; i < total8; i += stride) {
        f32x4 v0 = *reinterpret_cast<const f32x4*>(x + i * 8);
        f32x4 v1 = *reinterpret_cast<const f32x4*>(x + i * 8 + 4);
        short8 b;
#pragma unroll
        for (int j = 0; j < 4; ++j) b[j]     = (short)f2bf(v0[j]);
#pragma unroll
        for (int j = 0; j < 4; ++j) b[j + 4] = (short)f2bf(v1[j]);
        *reinterpret_cast<short8*>(xb + i * 8) = b;
    }
}

// ---------------------------------------------------------------------------
// Kernel 1: materialize W (bf16) from eigens.
// W[y*8+j][xb*8+c] = eigens[y][xb][(j-c)&7]
// ---------------------------------------------------------------------------
__global__ __launch_bounds__(256) void build_w(const float* __restrict__ eig,
                                               unsigned short* __restrict__ W) {
    int tid = blockIdx.x * 256 + threadIdx.x;   // 0..16383
    int y  = tid >> 7;
    int xb = tid & 127;
    const float* e = eig + (size_t)((y << 7) + xb) * 8;
    f32x4 e0 = *reinterpret_cast<const f32x4*>(e);
    f32x4 e1 = *reinterpret_cast<const f32x4*>(e + 4);
    float ev[8] = {e0[0], e0[1], e0[2], e0[3], e1[0], e1[1], e1[2], e1[3]};
#pragma unroll
    for (int j = 0; j < 8; ++j) {
        alignas(16) unsigned short wv[8];
#pragma unroll
        for (int c = 0; c < 8; ++c) wv[c] = f2bf(ev[(j - c) & 7]);
        *reinterpret_cast<uint4*>(W + (size_t)(y * 8 + j) * K_IN + xb * 8) =
            *reinterpret_cast<const uint4*>(wv);
    }
}

// ---------------------------------------------------------------------------
// Kernel 2 (fast path): C = A_bf16[M,K] * W[N,K]^T, m97 structure:
// 128x128 tile, BK=64, 4 waves (2x2 of 64x64), global_load_lds dwordx4
// staging with PRE-SWIZZLED global source (LDS image: LDS[row][c] =
// G[row][c ^ (row&7)], 16B chunks), swizzled ds_read_b128, 2 barriers/K-step.
// ---------------------------------------------------------------------------
__global__ __launch_bounds__(256) void gemm_bf16(const unsigned short* __restrict__ A,
                                                 const unsigned short* __restrict__ W,
                                                 float* __restrict__ C) {
    __shared__ unsigned short Alds[BM * BK];    // 16 KiB
    __shared__ unsigned short Blds[BN * BK];    // 16 KiB

    // XCD-aware bijective swizzle (nwg=2048, %8==0): each XCD walks the 8
    // N-blocks of one M-panel consecutively -> A panel + full W stay in L2.
    const int bid  = blockIdx.x;
    const int swz  = (bid & 7) * 256 + (bid >> 3);
    const int nblk = swz & 7;
    const int mblk = swz >> 3;
    const int brow = mblk * BM;
    const int bcol = nblk * BN;

    const int tid  = threadIdx.x;
    const int lane = tid & 63;
    const int wv   = tid >> 6;                   // wave 0..3
    const int wm   = wv >> 1;
    const int wn   = wv & 1;

    f32x4 acc[4][4];
    const f32x4 zero = {0.f, 0.f, 0.f, 0.f};
#pragma unroll
    for (int i = 0; i < 4; ++i)
#pragma unroll
        for (int j = 0; j < 4; ++j) acc[i][j] = zero;

    // Staging geometry: tile = 16 segments of 1024B; wave wv stages segments
    // wv*4+s (s=0..3). Segment base row = wv*32 + s*8. Lane l covers
    // row_in_seg = l>>3, chunk = l&7; source chunk pre-swizzled by row&7=l>>3.
    const int lrow = lane >> 3;                  // 0..7 == row&7
    const int lchk = (lane & 7) ^ lrow;          // swizzled source 16B chunk
    const size_t arow0 = (size_t)(brow + wv * 32 + lrow);
    const size_t brow0 = (size_t)(bcol + wv * 32 + lrow);
    const unsigned short* Abase = A + arow0 * K_IN + lchk * 8;
    const unsigned short* Bbase = W + brow0 * K_IN + lchk * 8;
    unsigned short* AldsBase = Alds + wv * 2048; // (wv*32)*64 elements
    unsigned short* BldsBase = Blds + wv * 2048;

    for (int kt = 0; kt < K_IN; kt += BK) {
        __syncthreads();                         // previous tile consumed
#pragma unroll
        for (int s = 0; s < 4; ++s) {
            gload_lds16(Abase + (size_t)(s * 8) * K_IN + kt, AldsBase + s * 512);
            gload_lds16(Bbase + (size_t)(s * 8) * K_IN + kt, BldsBase + s * 512);
        }
        __syncthreads();                         // vmcnt(0) drain + barrier
#pragma unroll
        for (int ks = 0; ks < 2; ++ks) {
            short8 af[4], bfr[4];
            const int cb = ks * 4 + (lane >> 4); // global 16B k-chunk 0..7
            const int sl = cb ^ (lane & 7);      // swizzled LDS slot
#pragma unroll
            for (int mt = 0; mt < 4; ++mt) {
                int row = wm * 64 + mt * 16 + (lane & 15);
                af[mt] = *reinterpret_cast<const short8*>(Alds + row * BK + sl * 8);
            }
#pragma unroll
            for (int nt = 0; nt < 4; ++nt) {
                int row = wn * 64 + nt * 16 + (lane & 15);
                bfr[nt] = *reinterpret_cast<const short8*>(Blds + row * BK + sl * 8);
            }
#pragma unroll
            for (int mt = 0; mt < 4; ++mt)
#pragma unroll
                for (int nt = 0; nt < 4; ++nt)
                    acc[mt][nt] = __builtin_amdgcn_mfma_f32_16x16x32_bf16(
                        af[mt], bfr[nt], acc[mt][nt], 0, 0, 0);
        }
    }

    // Epilogue: C/D layout col = lane&15, row = (lane>>4)*4 + reg
#pragma unroll
    for (int mt = 0; mt < 4; ++mt) {
#pragma unroll
        for (int nt = 0; nt < 4; ++nt) {
            int col = bcol + wn * 64 + nt * 16 + (lane & 15);
#pragma unroll
            for (int r = 0; r < 4; ++r) {
                int row = brow + wm * 64 + mt * 16 + (lane >> 4) * 4 + r;
                C[(size_t)row * N_OUT + col] = acc[mt][nt][r];
            }
        }
    }
}

// ---------------------------------------------------------------------------
// Fallback GEMM (round-1 verified): f32 A reg-staged, used if ws too small.
// ---------------------------------------------------------------------------
__global__ __launch_bounds__(256) void gemm_bt(const float* __restrict__ A,
                                               const unsigned short* __restrict__ W,
                                               float* __restrict__ C) {
    __shared__ unsigned short Alds[BM * BK];
    __shared__ unsigned short Blds[BN * BK];

    const int bid  = blockIdx.x;
    const int swz  = (bid & 7) * 256 + (bid >> 3);
    const int nblk = swz & 7;
    const int mblk = swz >> 3;
    const int brow = mblk * BM;
    const int bcol = nblk * BN;

    const int tid  = threadIdx.x;
    const int lane = tid & 63;
    const int wv   = tid >> 6;
    const int wm   = wv >> 1;
    const int wn   = wv & 1;

    f32x4 acc[4][4];
    const f32x4 zero = {0.f, 0.f, 0.f, 0.f};
#pragma unroll
    for (int i = 0; i < 4; ++i)
#pragma unroll
        for (int j = 0; j < 4; ++j) acc[i][j] = zero;

    const int srow  = tid >> 3;
    const int sslot = tid & 7;
    const int sk8   = sslot ^ (srow & 7);
    const float*          Abase = A + (size_t)(brow + srow) * K_IN + sk8 * 8;
    const unsigned short* Wbase = W + (size_t)(bcol + srow) * K_IN + sk8 * 8;
    unsigned short* AldsW = Alds + srow * BK + sslot * 8;
    unsigned short* BldsW = Blds + srow * BK + sslot * 8;

    for (int kt = 0; kt < K_IN; kt += BK) {
        __syncthreads();
#pragma unroll
        for (int it = 0; it < 4; ++it) {
            const float* src = Abase + (size_t)it * 32 * K_IN + kt;
            f32x4 v0 = *reinterpret_cast<const f32x4*>(src);
            f32x4 v1 = *reinterpret_cast<const f32x4*>(src + 4);
            short8 b;
#pragma unroll
            for (int i = 0; i < 4; ++i) b[i]     = (short)f2bf(v0[i]);
#pragma unroll
            for (int i = 0; i < 4; ++i) b[i + 4] = (short)f2bf(v1[i]);
            *reinterpret_cast<short8*>(AldsW + it * 32 * BK) = b;
        }
#pragma unroll
        for (int it = 0; it < 4; ++it) {
            const unsigned short* src = Wbase + (size_t)it * 32 * K_IN + kt;
            short8 b = *reinterpret_cast<const short8*>(src);
            *reinterpret_cast<short8*>(BldsW + it * 32 * BK) = b;
        }
        __syncthreads();
#pragma unroll
        for (int ks = 0; ks < 2; ++ks) {
            short8 af[4], bfr[4];
            const int cb = ks * 4 + (lane >> 4);
#pragma unroll
            for (int mt = 0; mt < 4; ++mt) {
                int row  = wm * 64 + mt * 16 + (lane & 15);
                int slot = cb ^ (row & 7);
                af[mt] = *reinterpret_cast<const short8*>(Alds + row * BK + slot * 8);
            }
#pragma unroll
            for (int nt = 0; nt < 4; ++nt) {
                int row  = wn * 64 + nt * 16 + (lane & 15);
                int slot = cb ^ (row & 7);
                bfr[nt] = *reinterpret_cast<const short8*>(Blds + row * BK + slot * 8);
            }
#pragma unroll
            for (int mt = 0; mt < 4; ++mt)
#pragma unroll
                for (int nt = 0; nt < 4; ++nt)
                    acc[mt][nt] = __builtin_amdgcn_mfma_f32_16x16x32_bf16(
                        af[mt], bfr[nt], acc[mt][nt], 0, 0, 0);
        }
    }

#pragma unroll
    for (int mt = 0; mt < 4; ++mt) {
#pragma unroll
        for (int nt = 0; nt < 4; ++nt) {
            int col = bcol + wn * 64 + nt * 16 + (lane & 15);
#pragma unroll
            for (int r = 0; r < 4; ++r) {
                int row = brow + wm * 64 + mt * 16 + (lane >> 4) * 4 + r;
                C[(size_t)row * N_OUT + col] = acc[mt][nt][r];
            }
        }
    }
}

extern "C" void kernel_launch(void* const* d_in, const int* in_sizes, int n_in,
                              void* d_out, int out_size, void* d_ws, size_t ws_size,
                              hipStream_t stream) {
    const float* x   = (const float*)d_in[0];    // [32768,1024] f32
    const float* eig = (const float*)d_in[1];    // [128,128,8]  f32
    float* out = (float*)d_out;                  // [32768,1024] f32

    const size_t XB     = (size_t)M_BATCH * K_IN;            // x elements
    const size_t W_ELTS = (size_t)N_OUT * K_IN;              // W elements
    const size_t need   = XB * sizeof(unsigned short) + W_ELTS * sizeof(unsigned short);

    if (ws_size >= need) {
        // fast path: x -> bf16 scratch, then m97-style bf16 GEMM
        unsigned short* xb = (unsigned short*)d_ws;
        unsigned short* W  = (unsigned short*)d_ws + XB;
        hipLaunchKernelGGL(cvt_x, dim3(2048), dim3(256), 0, stream, x, xb);
        hipLaunchKernelGGL(build_w, dim3(64), dim3(256), 0, stream, eig, W);
        hipLaunchKernelGGL(gemm_bf16, dim3((M_BATCH / BM) * (N_OUT / BN)), dim3(256),
                           0, stream, xb, W, out);
    } else if (ws_size >= W_ELTS * sizeof(unsigned short)) {
        // fallback: round-1 verified path
        unsigned short* W = (unsigned short*)d_ws;
        hipLaunchKernelGGL(build_w, dim3(64), dim3(256), 0, stream, eig, W);
        hipLaunchKernelGGL(gemm_bt, dim3((M_BATCH / BM) * (N_OUT / BN)), dim3(256),
                           0, stream, x, W, out);
    }
}